// Round 9
// baseline (424.094 us; speedup 1.0000x reference)
//
#include <hip/hip_runtime.h>
#include <hip/hip_bf16.h>
#include <math.h>

#define EMBED 1024
#define HEADS 16
#define HDIM 64
#define RANK 8
#define BB 2
#define TT 2048
#define MTOT (BB*TT)
#define BH (BB*HEADS)

typedef __attribute__((ext_vector_type(8))) short bf16x8;
typedef __attribute__((ext_vector_type(4))) float f32x4;
typedef unsigned short u16;
typedef unsigned int u32;

__device__ __forceinline__ u16 f2bf(float f){
  unsigned u = __float_as_uint(f);
  u += 0x7FFF + ((u >> 16) & 1);          // RNE
  return (u16)(u >> 16);
}
__device__ __forceinline__ float bf2f(u16 h){ return __uint_as_float(((unsigned)h) << 16); }

__device__ __forceinline__ u32 cvtpk(float lo, float hi){
  u32 r;
  asm("v_cvt_pk_bf16_f32 %0, %1, %2" : "=v"(r) : "v"(lo), "v"(hi));
  return r;
}

// raw v_exp_f32: computes 2^x in one instruction (logits are kept in log2 units)
__device__ __forceinline__ float fexp2(float x){
  float r;
  asm("v_exp_f32 %0, %1" : "=v"(r) : "v"(x));
  return r;
}

__device__ __forceinline__ void stage16(const void* g, void* l){
  __builtin_amdgcn_global_load_lds((const __attribute__((address_space(1))) unsigned int*)g,
                                   (__attribute__((address_space(3))) unsigned int*)l, 16, 0, 0);
}

// ---------------- prep kernels ----------------
__global__ void split_x_kernel(const float* __restrict__ x, u16* __restrict__ xhi, u16* __restrict__ xlo){
  int i = blockIdx.x * 256 + threadIdx.x;           // 4M
  float v = x[i];
  u16 h = f2bf(v);
  xhi[i] = h;
  xlo[i] = f2bf(v - bf2f(h));
}

// y = 0,1,2 : W_eff hi/lo split for Q/K/V.  y = 3 : plain bf16 cast of Wo.
__global__ void prep_weights_kernel(const float* __restrict__ W0, const float* __restrict__ W1,
                                    const float* __restrict__ W2, const float* __restrict__ W3,
                                    const float* __restrict__ A0, const float* __restrict__ A1,
                                    const float* __restrict__ A2,
                                    const float* __restrict__ B0, const float* __restrict__ B1,
                                    const float* __restrict__ B2,
                                    u16* __restrict__ whi, u16* __restrict__ wlo,
                                    u16* __restrict__ wob){
  int i = blockIdx.x * 256 + threadIdx.x;           // 1M per y
  int y = blockIdx.y;
  if (y == 3){ wob[i] = f2bf(W3[i]); return; }
  const float* W = (y == 0) ? W0 : (y == 1) ? W1 : W2;
  const float* A = (y == 0) ? A0 : (y == 1) ? A1 : A2;
  const float* Bm = (y == 0) ? B0 : (y == 1) ? B1 : B2;
  int o = i >> 10, c = i & 1023;
  float s = 0.f;
#pragma unroll
  for (int r = 0; r < RANK; ++r) s += A[c*RANK+r] * Bm[r*EMBED+o];
  float v = W[i] + 2.0f * s;
  u16 h = f2bf(v);
  size_t off = (size_t)y * 1048576 + i;
  whi[off] = h;
  wlo[off] = f2bf(v - bf2f(h));
}

__device__ __forceinline__ int swz4(int row){ return (row ^ (row >> 2)) & 3; }

// ---------------- fused QKV projection GEMM ----------------
__global__ __launch_bounds__(256)
void qkv_gemm(const u16* __restrict__ Ahi, const u16* __restrict__ Alo,
              const u16* __restrict__ Bhi, const u16* __restrict__ Blo,
              u16* __restrict__ qhi, u16* __restrict__ qlo,
              u16* __restrict__ khi, u16* __restrict__ klo,
              u16* __restrict__ vt)
{
  __shared__ __align__(16) u16 Ah[128*32], Bh[128*32], Al[128*32], Bl[128*32];
  const int t = threadIdx.x, lane = t & 63, w = t >> 6;
  const int wr = w >> 1, wc = w & 1;
  const int fr = lane & 15, fk = lane >> 4;
  const int m0 = blockIdx.y * 128, n0 = blockIdx.x * 128;
  const bool full = (n0 < 2048);

  f32x4 acc[4][4];
#pragma unroll
  for (int i = 0; i < 4; ++i)
#pragma unroll
    for (int j = 0; j < 4; ++j) acc[i][j] = (f32x4){0.f,0.f,0.f,0.f};

  for (int k0 = 0; k0 < EMBED; k0 += 32){
    __syncthreads();
#pragma unroll
    for (int cc = 0; cc < 2; ++cc){
      int cb = w*128 + cc*64;
      int chunk = cb + lane;
      int row = chunk >> 2, slot = chunk & 3;
      int sl = slot ^ swz4(row);
      stage16(Ahi + (size_t)(m0+row)*EMBED + k0 + sl*8, Ah + cb*8);
      stage16(Bhi + (size_t)(n0+row)*EMBED + k0 + sl*8, Bh + cb*8);
      if (full){
        stage16(Alo + (size_t)(m0+row)*EMBED + k0 + sl*8, Al + cb*8);
        stage16(Blo + (size_t)(n0+row)*EMBED + k0 + sl*8, Bl + cb*8);
      }
    }
    __syncthreads();

    bf16x8 ah[4], bh[4], al[4], bl[4];
#pragma unroll
    for (int i = 0; i < 4; ++i){
      int ra = wr*64 + i*16 + fr;
      int oa = ra*32 + (fk ^ swz4(ra))*8;
      ah[i] = *(const bf16x8*)&Ah[oa];
      if (full) al[i] = *(const bf16x8*)&Al[oa];
      int rb = wc*64 + i*16 + fr;
      int ob = rb*32 + (fk ^ swz4(rb))*8;
      bh[i] = *(const bf16x8*)&Bh[ob];
      if (full) bl[i] = *(const bf16x8*)&Bl[ob];
    }
#pragma unroll
    for (int i = 0; i < 4; ++i)
#pragma unroll
      for (int j = 0; j < 4; ++j){
        acc[i][j] = __builtin_amdgcn_mfma_f32_16x16x32_bf16(ah[i], bh[j], acc[i][j], 0,0,0);
        if (full){
          acc[i][j] = __builtin_amdgcn_mfma_f32_16x16x32_bf16(ah[i], bl[j], acc[i][j], 0,0,0);
          acc[i][j] = __builtin_amdgcn_mfma_f32_16x16x32_bf16(al[i], bh[j], acc[i][j], 0,0,0);
        }
      }
  }

  const int mat = (n0 + wc*64) >> 10;        // 0=Q 1=K 2=V (uniform per wave)
  const float QSCALE = 0.125f * 1.44269504089f;   // fold 1/sqrt(64) and log2(e)
#pragma unroll
  for (int i = 0; i < 4; ++i)
#pragma unroll
    for (int j = 0; j < 4; ++j)
#pragma unroll
      for (int r = 0; r < 4; ++r){
        int gm = m0 + wr*64 + i*16 + fk*4 + r;
        int gn = n0 + wc*64 + j*16 + fr;
        int col = gn & 1023;
        float v = acc[i][j][r];
        int b = gm >> 11, tt2 = gm & 2047, h = col >> 6, d = col & 63;
        if (mat == 2){
          vt[((size_t)(b*HEADS + h)*HDIM + d)*TT + tt2] = f2bf(v);
        } else {
          if (mat == 0) v *= QSCALE;
          size_t idx = ((size_t)(b*HEADS + h)*TT + tt2)*HDIM + d;
          u16 hi = f2bf(v);
          u16 lo = f2bf(v - bf2f(hi));
          if (mat == 0){ qhi[idx] = hi; qlo[idx] = lo; }
          else         { khi[idx] = hi; klo[idx] = lo; }
        }
      }
}

// ---------------- flash attention, MFMA, swapped QK^T, async reg-staging ----------------
// S^T = K Q^T via mfma(Kfrag, Qfrag): rows=kv, cols=q=fr. Per-lane softmax state.
// Logits in log2 units (Q pre-scaled by log2e/8). K/V tile t+1 loaded into
// registers during tile t's compute (pre-swizzled source), committed via
// ds_write_b128 to linear dest after the barrier (T14 async-STAGE split).
__global__ __launch_bounds__(256)
void attn_mfma(const u16* __restrict__ Qhi, const u16* __restrict__ Qlo,
               const u16* __restrict__ Khi, const u16* __restrict__ Klo,
               const u16* __restrict__ Vt,  u16* __restrict__ ctx)
{
  __shared__ __align__(16) u16 smem[16384];   // 32 KB
  u16* Kh = smem;            // 4096 (aliases Q staging)
  u16* Kl = smem + 4096;     // 4096
  u16* Vs = smem + 8192;     // 4096
  u16* Ps = smem + 12288;    // 4096 (4 waves x 1024)
  const int t = threadIdx.x, lane = t & 63, w = t >> 6;
  const int fr = lane & 15, fk = lane >> 4;
  const int bh = blockIdx.y, q0 = blockIdx.x * 64;
  const size_t kbase = (size_t)bh * TT * HDIM;
  const size_t vbase = (size_t)bh * HDIM * TT;

  // stage Q (into K region, gload_lds), pull to registers
#pragma unroll
  for (int cc = 0; cc < 2; ++cc){
    int cb = w*128 + cc*64;
    int chunk = cb + lane;
    int row = chunk >> 3, slot = chunk & 7;
    int sl = slot ^ (row & 7);
    stage16(Qhi + kbase + (size_t)(q0+row)*HDIM + sl*8, Kh + cb*8);
    stage16(Qlo + kbase + (size_t)(q0+row)*HDIM + sl*8, Kl + cb*8);
  }

  // per-thread staging addresses (pre-swizzled source, linear LDS dest)
  int dst[2];
  const u16 *pKh[2], *pKl[2], *pV[2];
#pragma unroll
  for (int cc = 0; cc < 2; ++cc){
    int chunk = w*128 + cc*64 + lane;
    int row = chunk >> 3, slot = chunk & 7;
    int sl = slot ^ (row & 7);
    dst[cc] = chunk * 8;
    pKh[cc] = Khi + kbase + (size_t)row*HDIM + sl*8;
    pKl[cc] = Klo + kbase + (size_t)row*HDIM + sl*8;
    pV [cc] = Vt  + vbase + (size_t)row*TT  + sl*8;
  }
  // preload tile 0 into registers
  uint4 rKh[2], rKl[2], rV[2];
#pragma unroll
  for (int cc = 0; cc < 2; ++cc){
    rKh[cc] = *(const uint4*)pKh[cc];  pKh[cc] += 64*HDIM;
    rKl[cc] = *(const uint4*)pKl[cc];  pKl[cc] += 64*HDIM;
    rV [cc] = *(const uint4*)pV [cc];  pV [cc] += 64;
  }

  __syncthreads();
  bf16x8 qh[2], ql[2];
#pragma unroll
  for (int ks = 0; ks < 2; ++ks){
    int row = w*16 + fr;
    int off = row*64 + ((ks*4 + fk) ^ (row & 7))*8;
    qh[ks] = *(const bf16x8*)&Kh[off];
    ql[ks] = *(const bf16x8*)&Kl[off];
  }

  float mi = -1e30f, li = 0.f;
  f32x4 oacc[4];
#pragma unroll
  for (int n = 0; n < 4; ++n) oacc[n] = (f32x4){0.f,0.f,0.f,0.f};

  for (int kt = 0; kt < TT/64; ++kt){
    __syncthreads();   // all waves done reading LDS (prev compute / q reg-loads)
    // commit staged tile (vmcnt waits inserted by compiler)
#pragma unroll
    for (int cc = 0; cc < 2; ++cc){
      *(uint4*)&Kh[dst[cc]] = rKh[cc];
      *(uint4*)&Kl[dst[cc]] = rKl[cc];
      *(uint4*)&Vs[dst[cc]] = rV[cc];
    }
    __syncthreads();
    // issue next-tile loads; latency hides under this tile's compute
    if (kt + 1 < TT/64){
#pragma unroll
      for (int cc = 0; cc < 2; ++cc){
        rKh[cc] = *(const uint4*)pKh[cc];  pKh[cc] += 64*HDIM;
        rKl[cc] = *(const uint4*)pKl[cc];  pKl[cc] += 64*HDIM;
        rV [cc] = *(const uint4*)pV [cc];  pV [cc] += 64;
      }
    }

    // S^T = K Q^T (3-MFMA hi/lo), rows=kv, cols=q=fr
    f32x4 sacc[4];
#pragma unroll
    for (int n = 0; n < 4; ++n) sacc[n] = (f32x4){0.f,0.f,0.f,0.f};
#pragma unroll
    for (int n = 0; n < 4; ++n)
#pragma unroll
      for (int ks = 0; ks < 2; ++ks){
        int row = n*16 + fr;
        int off = row*64 + ((ks*4 + fk) ^ (row & 7))*8;
        bf16x8 kh = *(const bf16x8*)&Kh[off];
        bf16x8 kl = *(const bf16x8*)&Kl[off];
        sacc[n] = __builtin_amdgcn_mfma_f32_16x16x32_bf16(kh, qh[ks], sacc[n], 0,0,0);
        sacc[n] = __builtin_amdgcn_mfma_f32_16x16x32_bf16(kl, qh[ks], sacc[n], 0,0,0);
        sacc[n] = __builtin_amdgcn_mfma_f32_16x16x32_bf16(kh, ql[ks], sacc[n], 0,0,0);
      }

    // per-lane tile max over this lane's 16 values, then across the 4 fk-groups
    float mt = fmaxf(fmaxf(sacc[0][0], sacc[0][1]), fmaxf(sacc[0][2], sacc[0][3]));
#pragma unroll
    for (int n = 1; n < 4; ++n)
      mt = fmaxf(mt, fmaxf(fmaxf(sacc[n][0], sacc[n][1]), fmaxf(sacc[n][2], sacc[n][3])));
    mt = fmaxf(mt, __shfl_xor(mt, 16));
    mt = fmaxf(mt, __shfl_xor(mt, 32));

    // defer-max (log2 units; 11.54 ~ e^8)
    if (__any(mt > mi + 11.54f)){
      float mn = fmaxf(mi, mt);
      float sc = fexp2(mi - mn);
      mi = mn;
      li *= sc;
      float sct[4];
#pragma unroll
      for (int r = 0; r < 4; ++r) sct[r] = __shfl(sc, fk*4 + r);
#pragma unroll
      for (int n = 0; n < 4; ++n)
#pragma unroll
        for (int r = 0; r < 4; ++r) oacc[n][r] *= sct[r];
    }

    // P = 2^(S - mi) via raw v_exp_f32, in-lane sum + 2 shuffles
    float rs = 0.f;
#pragma unroll
    for (int n = 0; n < 4; ++n)
#pragma unroll
      for (int r = 0; r < 4; ++r){
        float p = fexp2(sacc[n][r] - mi);
        sacc[n][r] = p;
        rs += p;
      }
    rs += __shfl_xor(rs, 16);
    rs += __shfl_xor(rs, 32);
    li += rs;

    // pack P (bf16 pairs) and write 4x ds_write_b64 into row q=fr
#pragma unroll
    for (int n = 0; n < 4; ++n){
      u32 u0 = cvtpk(sacc[n][0], sacc[n][1]);
      u32 u1 = cvtpk(sacc[n][2], sacc[n][3]);
      int slot = n*2 + (fk >> 1);
      int idx = w*1024 + fr*64 + (slot ^ (fr & 7))*8 + (fk & 1)*4;
      uint2 pk; pk.x = u0; pk.y = u1;
      *(uint2*)&Ps[idx] = pk;
    }

    // O += P V  (pa rows=q=fr -> output rows (fk,r)=q; V rows=d -> output cols fr=d)
#pragma unroll
    for (int ks = 0; ks < 2; ++ks){
      bf16x8 pa = *(const bf16x8*)&Ps[w*1024 + fr*64 + ((ks*4 + fk) ^ (fr & 7))*8];
#pragma unroll
      for (int n = 0; n < 4; ++n){
        int row = n*16 + fr;
        bf16x8 bv = *(const bf16x8*)&Vs[row*64 + ((ks*4 + fk) ^ (row & 7))*8];
        oacc[n] = __builtin_amdgcn_mfma_f32_16x16x32_bf16(pa, bv, oacc[n], 0,0,0);
      }
    }
  }

  // finalize: inv lives at q=fr lanes; transpose to (fk,r) rows
  float inv = 1.f / li;
  float invt[4];
#pragma unroll
  for (int r = 0; r < 4; ++r) invt[r] = __shfl(inv, fk*4 + r);

  int b = bh >> 4, h = bh & 15;
#pragma unroll
  for (int r = 0; r < 4; ++r){
    int q = q0 + w*16 + fk*4 + r;
#pragma unroll
    for (int n = 0; n < 4; ++n){
      int d = n*16 + fr;
      ctx[((size_t)(b*TT + q))*EMBED + h*HDIM + d] = f2bf(oacc[n][r]*invt[r]);
    }
  }
}

// ---------------- output projection (bf16 MFMA, fp32 + bias out) ----------------
__global__ __launch_bounds__(256)
void outproj_gemm(const u16* __restrict__ Ab, const u16* __restrict__ Bb,
                  const float* __restrict__ bias, float* __restrict__ C)
{
  __shared__ __align__(16) u16 Ah[128*32], Bh[128*32];
  const int t = threadIdx.x, lane = t & 63, w = t >> 6;
  const int wr = w >> 1, wc = w & 1;
  const int fr = lane & 15, fk = lane >> 4;
  const int m0 = blockIdx.y * 128, n0 = blockIdx.x * 128;

  f32x4 acc[4][4];
#pragma unroll
  for (int i = 0; i < 4; ++i)
#pragma unroll
    for (int j = 0; j < 4; ++j) acc[i][j] = (f32x4){0.f,0.f,0.f,0.f};

  for (int k0 = 0; k0 < EMBED; k0 += 32){
    __syncthreads();
#pragma unroll
    for (int cc = 0; cc < 2; ++cc){
      int cb = w*128 + cc*64;
      int chunk = cb + lane;
      int row = chunk >> 2, slot = chunk & 3;
      int sl = slot ^ swz4(row);
      stage16(Ab + (size_t)(m0+row)*EMBED + k0 + sl*8, Ah + cb*8);
      stage16(Bb + (size_t)(n0+row)*EMBED + k0 + sl*8, Bh + cb*8);
    }
    __syncthreads();

    bf16x8 ah[4], bh[4];
#pragma unroll
    for (int i = 0; i < 4; ++i){
      int ra = wr*64 + i*16 + fr;
      ah[i] = *(const bf16x8*)&Ah[ra*32 + (fk ^ swz4(ra))*8];
      int rb = wc*64 + i*16 + fr;
      bh[i] = *(const bf16x8*)&Bh[rb*32 + (fk ^ swz4(rb))*8];
    }
#pragma unroll
    for (int i = 0; i < 4; ++i)
#pragma unroll
      for (int j = 0; j < 4; ++j)
        acc[i][j] = __builtin_amdgcn_mfma_f32_16x16x32_bf16(ah[i], bh[j], acc[i][j], 0,0,0);
  }

#pragma unroll
  for (int i = 0; i < 4; ++i)
#pragma unroll
    for (int j = 0; j < 4; ++j)
#pragma unroll
      for (int r = 0; r < 4; ++r){
        int gm = m0 + wr*64 + i*16 + fk*4 + r;
        int gn = n0 + wc*64 + j*16 + fr;
        C[(size_t)gm*EMBED + gn] = acc[i][j][r] + bias[gn];
      }
}

// ---------------- launch ----------------
extern "C" void kernel_launch(void* const* d_in, const int* in_sizes, int n_in,
                              void* d_out, int out_size, void* d_ws, size_t ws_size,
                              hipStream_t stream) {
  const float* x  = (const float*)d_in[0];
  const float* Wq = (const float*)d_in[1];
  const float* Aq = (const float*)d_in[2];
  const float* Bq = (const float*)d_in[3];
  const float* Wk = (const float*)d_in[4];
  const float* Ak = (const float*)d_in[5];
  const float* Bk = (const float*)d_in[6];
  const float* Wv = (const float*)d_in[7];
  const float* Av = (const float*)d_in[8];
  const float* Bv = (const float*)d_in[9];
  const float* Wo = (const float*)d_in[10];
  const float* bo = (const float*)d_in[11];
  float* out = (float*)d_out;

  char* ws = (char*)d_ws;
  const size_t MB = 1u << 20;
  u16* xhi  = (u16*)(ws + 0*MB);    // 8 MB (aliased by ctx later)
  u16* xlo  = (u16*)(ws + 8*MB);    // 8 MB
  u16* whi  = (u16*)(ws + 16*MB);   // 6 MB  [Wq;Wk;Wv] hi
  u16* wlo  = (u16*)(ws + 22*MB);   // 6 MB
  u16* wob  = (u16*)(ws + 28*MB);   // 2 MB
  u16* qhi  = (u16*)(ws + 30*MB);   // 8 MB
  u16* qlo  = (u16*)(ws + 38*MB);   // 8 MB
  u16* khi  = (u16*)(ws + 46*MB);   // 8 MB
  u16* klo  = (u16*)(ws + 54*MB);   // 8 MB
  u16* vt   = (u16*)(ws + 62*MB);   // 8 MB
  u16* ctx  = (u16*)(ws + 0*MB);    // 8 MB, over xhi (dead after qkv_gemm)

  dim3 blk(256);
  split_x_kernel<<<dim3(MTOT*EMBED/256), blk, 0, stream>>>(x, xhi, xlo);
  prep_weights_kernel<<<dim3(4096, 4), blk, 0, stream>>>(Wq, Wk, Wv, Wo, Aq, Ak, Av,
                                                         Bq, Bk, Bv, whi, wlo, wob);

  qkv_gemm<<<dim3(3*EMBED/128, MTOT/128), blk, 0, stream>>>(xhi, xlo, whi, wlo,
                                                            qhi, qlo, khi, klo, vt);

  attn_mfma<<<dim3(TT/64, BH), blk, 0, stream>>>(qhi, qlo, khi, klo, vt, ctx);

  outproj_gemm<<<dim3(EMBED/128, MTOT/128), blk, 0, stream>>>(ctx, wob, bo, out);
}

// Round 11
// 291.761 us; speedup vs baseline: 1.4536x; 1.4536x over previous
//
#include <hip/hip_runtime.h>
#include <hip/hip_bf16.h>
#include <math.h>

#define EMBED 1024
#define HEADS 16
#define HDIM 64
#define RANK 8
#define BB 2
#define TT 2048
#define MTOT (BB*TT)
#define BH (BB*HEADS)

typedef __attribute__((ext_vector_type(8))) short bf16x8;
typedef __attribute__((ext_vector_type(4))) float f32x4;
typedef unsigned short u16;
typedef unsigned int u32;

__device__ __forceinline__ u16 f2bf(float f){
  unsigned u = __float_as_uint(f);
  u += 0x7FFF + ((u >> 16) & 1);          // RNE
  return (u16)(u >> 16);
}
__device__ __forceinline__ float bf2f(u16 h){ return __uint_as_float(((unsigned)h) << 16); }

__device__ __forceinline__ u32 cvtpk(float lo, float hi){
  u32 r;
  asm("v_cvt_pk_bf16_f32 %0, %1, %2" : "=v"(r) : "v"(lo), "v"(hi));
  return r;
}

// raw v_exp_f32: computes 2^x in one instruction (logits are kept in log2 units)
__device__ __forceinline__ float fexp2(float x){
  float r;
  asm("v_exp_f32 %0, %1" : "=v"(r) : "v"(x));
  return r;
}

__device__ __forceinline__ void stage16(const void* g, void* l){
  __builtin_amdgcn_global_load_lds((const __attribute__((address_space(1))) unsigned int*)g,
                                   (__attribute__((address_space(3))) unsigned int*)l, 16, 0, 0);
}

// ---------------- prep kernels ----------------
__global__ void split_x_kernel(const float* __restrict__ x, u16* __restrict__ xhi, u16* __restrict__ xlo){
  int i = blockIdx.x * 256 + threadIdx.x;           // 4M
  float v = x[i];
  u16 h = f2bf(v);
  xhi[i] = h;
  xlo[i] = f2bf(v - bf2f(h));
}

// y = 0,1,2 : W_eff hi/lo split for Q/K/V.  y = 3 : plain bf16 cast of Wo.
__global__ void prep_weights_kernel(const float* __restrict__ W0, const float* __restrict__ W1,
                                    const float* __restrict__ W2, const float* __restrict__ W3,
                                    const float* __restrict__ A0, const float* __restrict__ A1,
                                    const float* __restrict__ A2,
                                    const float* __restrict__ B0, const float* __restrict__ B1,
                                    const float* __restrict__ B2,
                                    u16* __restrict__ whi, u16* __restrict__ wlo,
                                    u16* __restrict__ wob){
  int i = blockIdx.x * 256 + threadIdx.x;           // 1M per y
  int y = blockIdx.y;
  if (y == 3){ wob[i] = f2bf(W3[i]); return; }
  const float* W = (y == 0) ? W0 : (y == 1) ? W1 : W2;
  const float* A = (y == 0) ? A0 : (y == 1) ? A1 : A2;
  const float* Bm = (y == 0) ? B0 : (y == 1) ? B1 : B2;
  int o = i >> 10, c = i & 1023;
  float s = 0.f;
#pragma unroll
  for (int r = 0; r < RANK; ++r) s += A[c*RANK+r] * Bm[r*EMBED+o];
  float v = W[i] + 2.0f * s;
  u16 h = f2bf(v);
  size_t off = (size_t)y * 1048576 + i;
  whi[off] = h;
  wlo[off] = f2bf(v - bf2f(h));
}

__device__ __forceinline__ int swz4(int row){ return (row ^ (row >> 2)) & 3; }

// ---------------- fused QKV projection GEMM ----------------
__global__ __launch_bounds__(256)
void qkv_gemm(const u16* __restrict__ Ahi, const u16* __restrict__ Alo,
              const u16* __restrict__ Bhi, const u16* __restrict__ Blo,
              u16* __restrict__ qhi, u16* __restrict__ qlo,
              u16* __restrict__ khi, u16* __restrict__ klo,
              u16* __restrict__ vt)
{
  __shared__ __align__(16) u16 Ah[128*32], Bh[128*32], Al[128*32], Bl[128*32];
  const int t = threadIdx.x, lane = t & 63, w = t >> 6;
  const int wr = w >> 1, wc = w & 1;
  const int fr = lane & 15, fk = lane >> 4;
  const int m0 = blockIdx.y * 128, n0 = blockIdx.x * 128;
  const bool full = (n0 < 2048);

  f32x4 acc[4][4];
#pragma unroll
  for (int i = 0; i < 4; ++i)
#pragma unroll
    for (int j = 0; j < 4; ++j) acc[i][j] = (f32x4){0.f,0.f,0.f,0.f};

  for (int k0 = 0; k0 < EMBED; k0 += 32){
    __syncthreads();
#pragma unroll
    for (int cc = 0; cc < 2; ++cc){
      int cb = w*128 + cc*64;
      int chunk = cb + lane;
      int row = chunk >> 2, slot = chunk & 3;
      int sl = slot ^ swz4(row);
      stage16(Ahi + (size_t)(m0+row)*EMBED + k0 + sl*8, Ah + cb*8);
      stage16(Bhi + (size_t)(n0+row)*EMBED + k0 + sl*8, Bh + cb*8);
      if (full){
        stage16(Alo + (size_t)(m0+row)*EMBED + k0 + sl*8, Al + cb*8);
        stage16(Blo + (size_t)(n0+row)*EMBED + k0 + sl*8, Bl + cb*8);
      }
    }
    __syncthreads();

    bf16x8 ah[4], bh[4], al[4], bl[4];
#pragma unroll
    for (int i = 0; i < 4; ++i){
      int ra = wr*64 + i*16 + fr;
      int oa = ra*32 + (fk ^ swz4(ra))*8;
      ah[i] = *(const bf16x8*)&Ah[oa];
      if (full) al[i] = *(const bf16x8*)&Al[oa];
      int rb = wc*64 + i*16 + fr;
      int ob = rb*32 + (fk ^ swz4(rb))*8;
      bh[i] = *(const bf16x8*)&Bh[ob];
      if (full) bl[i] = *(const bf16x8*)&Bl[ob];
    }
#pragma unroll
    for (int i = 0; i < 4; ++i)
#pragma unroll
      for (int j = 0; j < 4; ++j){
        acc[i][j] = __builtin_amdgcn_mfma_f32_16x16x32_bf16(ah[i], bh[j], acc[i][j], 0,0,0);
        if (full){
          acc[i][j] = __builtin_amdgcn_mfma_f32_16x16x32_bf16(ah[i], bl[j], acc[i][j], 0,0,0);
          acc[i][j] = __builtin_amdgcn_mfma_f32_16x16x32_bf16(al[i], bh[j], acc[i][j], 0,0,0);
        }
      }
  }

  const int mat = (n0 + wc*64) >> 10;        // 0=Q 1=K 2=V (uniform per wave)
  const float QSCALE = 0.125f * 1.44269504089f;   // fold 1/sqrt(64) and log2(e)
#pragma unroll
  for (int i = 0; i < 4; ++i)
#pragma unroll
    for (int j = 0; j < 4; ++j)
#pragma unroll
      for (int r = 0; r < 4; ++r){
        int gm = m0 + wr*64 + i*16 + fk*4 + r;
        int gn = n0 + wc*64 + j*16 + fr;
        int col = gn & 1023;
        float v = acc[i][j][r];
        int b = gm >> 11, tt2 = gm & 2047, h = col >> 6, d = col & 63;
        if (mat == 2){
          vt[((size_t)(b*HEADS + h)*HDIM + d)*TT + tt2] = f2bf(v);
        } else {
          if (mat == 0) v *= QSCALE;
          size_t idx = ((size_t)(b*HEADS + h)*TT + tt2)*HDIM + d;
          u16 hi = f2bf(v);
          u16 lo = f2bf(v - bf2f(hi));
          if (mat == 0){ qhi[idx] = hi; qlo[idx] = lo; }
          else         { khi[idx] = hi; klo[idx] = lo; }
        }
      }
}

// ---------------- flash attention, MFMA, swapped QK^T ----------------
// S^T = K Q^T via mfma(Kfrag, Qfrag): rows=kv=(fk*4+r), cols=q=fr.
// Per-lane softmax state for q-row fr. Logits in log2 units (Q pre-scaled by log2e/8).
// Staging: global_load_lds direct (R9 lesson: reg-staging spilled to scratch).
__global__ __launch_bounds__(256)
void attn_mfma(const u16* __restrict__ Qhi, const u16* __restrict__ Qlo,
               const u16* __restrict__ Khi, const u16* __restrict__ Klo,
               const u16* __restrict__ Vt,  u16* __restrict__ ctx)
{
  __shared__ __align__(16) u16 smem[16384];   // 32 KB
  u16* Kh = smem;            // 4096 (aliases Q staging)
  u16* Kl = smem + 4096;     // 4096
  u16* Vs = smem + 8192;     // 4096
  u16* Ps = smem + 12288;    // 4096 (4 waves x 1024)
  const int t = threadIdx.x, lane = t & 63, w = t >> 6;
  const int fr = lane & 15, fk = lane >> 4;
  const int bh = blockIdx.y, q0 = blockIdx.x * 64;
  const size_t kbase = (size_t)bh * TT * HDIM;
  const size_t vbase = (size_t)bh * HDIM * TT;

  // stage Q (into K region), pull to registers
#pragma unroll
  for (int cc = 0; cc < 2; ++cc){
    int cb = w*128 + cc*64;
    int chunk = cb + lane;
    int row = chunk >> 3, slot = chunk & 7;
    int sl = slot ^ (row & 7);
    stage16(Qhi + kbase + (size_t)(q0+row)*HDIM + sl*8, Kh + cb*8);
    stage16(Qlo + kbase + (size_t)(q0+row)*HDIM + sl*8, Kl + cb*8);
  }
  __syncthreads();
  bf16x8 qh[2], ql[2];
#pragma unroll
  for (int ks = 0; ks < 2; ++ks){
    int row = w*16 + fr;
    int off = row*64 + ((ks*4 + fk) ^ (row & 7))*8;
    qh[ks] = *(const bf16x8*)&Kh[off];
    ql[ks] = *(const bf16x8*)&Kl[off];
  }

  float mi = -1e30f, li = 0.f;
  f32x4 oacc[4];
#pragma unroll
  for (int n = 0; n < 4; ++n) oacc[n] = (f32x4){0.f,0.f,0.f,0.f};

  for (int kt = 0; kt < TT/64; ++kt){
    int kv0 = kt * 64;
    __syncthreads();   // K/V buffers free (first iter: q reg-loads drained)
#pragma unroll
    for (int cc = 0; cc < 2; ++cc){
      int cb = w*128 + cc*64;
      int chunk = cb + lane;
      int row = chunk >> 3, slot = chunk & 7;
      int sl = slot ^ (row & 7);
      stage16(Khi + kbase + (size_t)(kv0+row)*HDIM + sl*8, Kh + cb*8);
      stage16(Klo + kbase + (size_t)(kv0+row)*HDIM + sl*8, Kl + cb*8);
      stage16(Vt  + vbase + (size_t)row*TT + kv0 + sl*8,  Vs + cb*8);
    }
    __syncthreads();

    // S^T = K Q^T (3-MFMA hi/lo), rows=kv, cols=q=fr
    f32x4 sacc[4];
#pragma unroll
    for (int n = 0; n < 4; ++n) sacc[n] = (f32x4){0.f,0.f,0.f,0.f};
#pragma unroll
    for (int n = 0; n < 4; ++n)
#pragma unroll
      for (int ks = 0; ks < 2; ++ks){
        int row = n*16 + fr;
        int off = row*64 + ((ks*4 + fk) ^ (row & 7))*8;
        bf16x8 kh = *(const bf16x8*)&Kh[off];
        bf16x8 kl = *(const bf16x8*)&Kl[off];
        sacc[n] = __builtin_amdgcn_mfma_f32_16x16x32_bf16(kh, qh[ks], sacc[n], 0,0,0);
        sacc[n] = __builtin_amdgcn_mfma_f32_16x16x32_bf16(kl, qh[ks], sacc[n], 0,0,0);
        sacc[n] = __builtin_amdgcn_mfma_f32_16x16x32_bf16(kh, ql[ks], sacc[n], 0,0,0);
      }

    // per-lane tile max over this lane's 16 values, then across the 4 fk-groups
    float mt = fmaxf(fmaxf(sacc[0][0], sacc[0][1]), fmaxf(sacc[0][2], sacc[0][3]));
#pragma unroll
    for (int n = 1; n < 4; ++n)
      mt = fmaxf(mt, fmaxf(fmaxf(sacc[n][0], sacc[n][1]), fmaxf(sacc[n][2], sacc[n][3])));
    mt = fmaxf(mt, __shfl_xor(mt, 16));
    mt = fmaxf(mt, __shfl_xor(mt, 32));

    // defer-max (log2 units; 11.54 ~ e^8)
    if (__any(mt > mi + 11.54f)){
      float mn = fmaxf(mi, mt);
      float sc = fexp2(mi - mn);
      mi = mn;
      li *= sc;
      float sct[4];
#pragma unroll
      for (int r = 0; r < 4; ++r) sct[r] = __shfl(sc, fk*4 + r);
#pragma unroll
      for (int n = 0; n < 4; ++n)
#pragma unroll
        for (int r = 0; r < 4; ++r) oacc[n][r] *= sct[r];
    }

    // P = 2^(S - mi) via raw v_exp_f32, in-lane sum + 2 shuffles
    float rs = 0.f;
#pragma unroll
    for (int n = 0; n < 4; ++n)
#pragma unroll
      for (int r = 0; r < 4; ++r){
        float p = fexp2(sacc[n][r] - mi);
        sacc[n][r] = p;
        rs += p;
      }
    rs += __shfl_xor(rs, 16);
    rs += __shfl_xor(rs, 32);
    li += rs;

    // pack P (bf16 pairs) and write 4x ds_write_b64 into row q=fr
#pragma unroll
    for (int n = 0; n < 4; ++n){
      u32 u0 = cvtpk(sacc[n][0], sacc[n][1]);
      u32 u1 = cvtpk(sacc[n][2], sacc[n][3]);
      int slot = n*2 + (fk >> 1);
      int idx = w*1024 + fr*64 + (slot ^ (fr & 7))*8 + (fk & 1)*4;
      uint2 pk; pk.x = u0; pk.y = u1;
      *(uint2*)&Ps[idx] = pk;
    }

    // O += P V  (pa rows=q=fr -> output rows (fk,r)=q; V rows=d -> output cols fr=d)
#pragma unroll
    for (int ks = 0; ks < 2; ++ks){
      bf16x8 pa = *(const bf16x8*)&Ps[w*1024 + fr*64 + ((ks*4 + fk) ^ (fr & 7))*8];
#pragma unroll
      for (int n = 0; n < 4; ++n){
        int row = n*16 + fr;
        bf16x8 bv = *(const bf16x8*)&Vs[row*64 + ((ks*4 + fk) ^ (row & 7))*8];
        oacc[n] = __builtin_amdgcn_mfma_f32_16x16x32_bf16(pa, bv, oacc[n], 0,0,0);
      }
    }
  }

  // finalize: inv lives at q=fr lanes; transpose to (fk,r) rows
  float inv = 1.f / li;
  float invt[4];
#pragma unroll
  for (int r = 0; r < 4; ++r) invt[r] = __shfl(inv, fk*4 + r);

  int b = bh >> 4, h = bh & 15;
#pragma unroll
  for (int r = 0; r < 4; ++r){
    int q = q0 + w*16 + fk*4 + r;
#pragma unroll
    for (int n = 0; n < 4; ++n){
      int d = n*16 + fr;
      ctx[((size_t)(b*TT + q))*EMBED + h*HDIM + d] = f2bf(oacc[n][r]*invt[r]);
    }
  }
}

// ---------------- output projection (bf16 MFMA, fp32 + bias out) ----------------
__global__ __launch_bounds__(256)
void outproj_gemm(const u16* __restrict__ Ab, const u16* __restrict__ Bb,
                  const float* __restrict__ bias, float* __restrict__ C)
{
  __shared__ __align__(16) u16 Ah[128*32], Bh[128*32];
  const int t = threadIdx.x, lane = t & 63, w = t >> 6;
  const int wr = w >> 1, wc = w & 1;
  const int fr = lane & 15, fk = lane >> 4;
  const int m0 = blockIdx.y * 128, n0 = blockIdx.x * 128;

  f32x4 acc[4][4];
#pragma unroll
  for (int i = 0; i < 4; ++i)
#pragma unroll
    for (int j = 0; j < 4; ++j) acc[i][j] = (f32x4){0.f,0.f,0.f,0.f};

  for (int k0 = 0; k0 < EMBED; k0 += 32){
    __syncthreads();
#pragma unroll
    for (int cc = 0; cc < 2; ++cc){
      int cb = w*128 + cc*64;
      int chunk = cb + lane;
      int row = chunk >> 2, slot = chunk & 3;
      int sl = slot ^ swz4(row);
      stage16(Ab + (size_t)(m0+row)*EMBED + k0 + sl*8, Ah + cb*8);
      stage16(Bb + (size_t)(n0+row)*EMBED + k0 + sl*8, Bh + cb*8);
    }
    __syncthreads();

    bf16x8 ah[4], bh[4];
#pragma unroll
    for (int i = 0; i < 4; ++i){
      int ra = wr*64 + i*16 + fr;
      ah[i] = *(const bf16x8*)&Ah[ra*32 + (fk ^ swz4(ra))*8];
      int rb = wc*64 + i*16 + fr;
      bh[i] = *(const bf16x8*)&Bh[rb*32 + (fk ^ swz4(rb))*8];
    }
#pragma unroll
    for (int i = 0; i < 4; ++i)
#pragma unroll
      for (int j = 0; j < 4; ++j)
        acc[i][j] = __builtin_amdgcn_mfma_f32_16x16x32_bf16(ah[i], bh[j], acc[i][j], 0,0,0);
  }

#pragma unroll
  for (int i = 0; i < 4; ++i)
#pragma unroll
    for (int j = 0; j < 4; ++j)
#pragma unroll
      for (int r = 0; r < 4; ++r){
        int gm = m0 + wr*64 + i*16 + fk*4 + r;
        int gn = n0 + wc*64 + j*16 + fr;
        C[(size_t)gm*EMBED + gn] = acc[i][j][r] + bias[gn];
      }
}

// ---------------- launch ----------------
extern "C" void kernel_launch(void* const* d_in, const int* in_sizes, int n_in,
                              void* d_out, int out_size, void* d_ws, size_t ws_size,
                              hipStream_t stream) {
  const float* x  = (const float*)d_in[0];
  const float* Wq = (const float*)d_in[1];
  const float* Aq = (const float*)d_in[2];
  const float* Bq = (const float*)d_in[3];
  const float* Wk = (const float*)d_in[4];
  const float* Ak = (const float*)d_in[5];
  const float* Bk = (const float*)d_in[6];
  const float* Wv = (const float*)d_in[7];
  const float* Av = (const float*)d_in[8];
  const float* Bv = (const float*)d_in[9];
  const float* Wo = (const float*)d_in[10];
  const float* bo = (const float*)d_in[11];
  float* out = (float*)d_out;

  char* ws = (char*)d_ws;
  const size_t MB = 1u << 20;
  u16* xhi  = (u16*)(ws + 0*MB);    // 8 MB (aliased by ctx later)
  u16* xlo  = (u16*)(ws + 8*MB);    // 8 MB
  u16* whi  = (u16*)(ws + 16*MB);   // 6 MB  [Wq;Wk;Wv] hi
  u16* wlo  = (u16*)(ws + 22*MB);   // 6 MB
  u16* wob  = (u16*)(ws + 28*MB);   // 2 MB
  u16* qhi  = (u16*)(ws + 30*MB);   // 8 MB
  u16* qlo  = (u16*)(ws + 38*MB);   // 8 MB
  u16* khi  = (u16*)(ws + 46*MB);   // 8 MB
  u16* klo  = (u16*)(ws + 54*MB);   // 8 MB
  u16* vt   = (u16*)(ws + 62*MB);   // 8 MB
  u16* ctx  = (u16*)(ws + 0*MB);    // 8 MB, over xhi (dead after qkv_gemm)

  dim3 blk(256);
  split_x_kernel<<<dim3(MTOT*EMBED/256), blk, 0, stream>>>(x, xhi, xlo);
  prep_weights_kernel<<<dim3(4096, 4), blk, 0, stream>>>(Wq, Wk, Wv, Wo, Aq, Ak, Av,
                                                         Bq, Bk, Bv, whi, wlo, wob);

  qkv_gemm<<<dim3(3*EMBED/128, MTOT/128), blk, 0, stream>>>(xhi, xlo, whi, wlo,
                                                            qhi, qlo, khi, klo, vt);

  attn_mfma<<<dim3(TT/64, BH), blk, 0, stream>>>(qhi, qlo, khi, klo, vt, ctx);

  outproj_gemm<<<dim3(EMBED/128, MTOT/128), blk, 0, stream>>>(ctx, wob, bo, out);
}

// Round 14
// 279.331 us; speedup vs baseline: 1.5182x; 1.0445x over previous
//
#include <hip/hip_runtime.h>
#include <hip/hip_bf16.h>
#include <math.h>

#define EMBED 1024
#define HEADS 16
#define HDIM 64
#define RANK 8
#define BB 2
#define TT 2048
#define MTOT (BB*TT)
#define BH (BB*HEADS)

typedef __attribute__((ext_vector_type(8))) short bf16x8;
typedef __attribute__((ext_vector_type(4))) float f32x4;
typedef unsigned short u16;
typedef unsigned int u32;

__device__ __forceinline__ u16 f2bf(float f){
  unsigned u = __float_as_uint(f);
  u += 0x7FFF + ((u >> 16) & 1);          // RNE
  return (u16)(u >> 16);
}
__device__ __forceinline__ float bf2f(u16 h){ return __uint_as_float(((unsigned)h) << 16); }

__device__ __forceinline__ u32 cvtpk(float lo, float hi){
  u32 r;
  asm("v_cvt_pk_bf16_f32 %0, %1, %2" : "=v"(r) : "v"(lo), "v"(hi));
  return r;
}

// raw v_exp_f32: computes 2^x in one instruction (logits are kept in log2 units)
__device__ __forceinline__ float fexp2(float x){
  float r;
  asm("v_exp_f32 %0, %1" : "=v"(r) : "v"(x));
  return r;
}

__device__ __forceinline__ void stage16(const void* g, void* l){
  __builtin_amdgcn_global_load_lds((const __attribute__((address_space(1))) unsigned int*)g,
                                   (__attribute__((address_space(3))) unsigned int*)l, 16, 0, 0);
}

// ---------------- prep kernels ----------------
__global__ void split_x_kernel(const float* __restrict__ x, u16* __restrict__ xhi, u16* __restrict__ xlo){
  int i = blockIdx.x * 256 + threadIdx.x;           // 4M
  float v = x[i];
  u16 h = f2bf(v);
  xhi[i] = h;
  xlo[i] = f2bf(v - bf2f(h));
}

// y = 0,1,2 : W_eff hi/lo split for Q/K/V.  y = 3 : plain bf16 cast of Wo.
__global__ void prep_weights_kernel(const float* __restrict__ W0, const float* __restrict__ W1,
                                    const float* __restrict__ W2, const float* __restrict__ W3,
                                    const float* __restrict__ A0, const float* __restrict__ A1,
                                    const float* __restrict__ A2,
                                    const float* __restrict__ B0, const float* __restrict__ B1,
                                    const float* __restrict__ B2,
                                    u16* __restrict__ whi, u16* __restrict__ wlo,
                                    u16* __restrict__ wob){
  int i = blockIdx.x * 256 + threadIdx.x;           // 1M per y
  int y = blockIdx.y;
  if (y == 3){ wob[i] = f2bf(W3[i]); return; }
  const float* W = (y == 0) ? W0 : (y == 1) ? W1 : W2;
  const float* A = (y == 0) ? A0 : (y == 1) ? A1 : A2;
  const float* Bm = (y == 0) ? B0 : (y == 1) ? B1 : B2;
  int o = i >> 10, c = i & 1023;
  float s = 0.f;
#pragma unroll
  for (int r = 0; r < RANK; ++r) s += A[c*RANK+r] * Bm[r*EMBED+o];
  float v = W[i] + 2.0f * s;
  u16 h = f2bf(v);
  size_t off = (size_t)y * 1048576 + i;
  whi[off] = h;
  wlo[off] = f2bf(v - bf2f(h));
}

__device__ __forceinline__ int swz4(int row){ return (row ^ (row >> 2)) & 3; }

// ---------------- fused QKV projection GEMM ----------------
__global__ __launch_bounds__(256)
void qkv_gemm(const u16* __restrict__ Ahi, const u16* __restrict__ Alo,
              const u16* __restrict__ Bhi, const u16* __restrict__ Blo,
              u16* __restrict__ qhi, u16* __restrict__ qlo,
              u16* __restrict__ khi, u16* __restrict__ klo,
              u16* __restrict__ vt)
{
  __shared__ __align__(16) u16 Ah[128*32], Bh[128*32], Al[128*32], Bl[128*32];
  const int t = threadIdx.x, lane = t & 63, w = t >> 6;
  const int wr = w >> 1, wc = w & 1;
  const int fr = lane & 15, fk = lane >> 4;
  const int m0 = blockIdx.y * 128, n0 = blockIdx.x * 128;
  const bool full = (n0 < 2048);

  f32x4 acc[4][4];
#pragma unroll
  for (int i = 0; i < 4; ++i)
#pragma unroll
    for (int j = 0; j < 4; ++j) acc[i][j] = (f32x4){0.f,0.f,0.f,0.f};

  for (int k0 = 0; k0 < EMBED; k0 += 32){
    __syncthreads();
#pragma unroll
    for (int cc = 0; cc < 2; ++cc){
      int cb = w*128 + cc*64;
      int chunk = cb + lane;
      int row = chunk >> 2, slot = chunk & 3;
      int sl = slot ^ swz4(row);
      stage16(Ahi + (size_t)(m0+row)*EMBED + k0 + sl*8, Ah + cb*8);
      stage16(Bhi + (size_t)(n0+row)*EMBED + k0 + sl*8, Bh + cb*8);
      if (full){
        stage16(Alo + (size_t)(m0+row)*EMBED + k0 + sl*8, Al + cb*8);
        stage16(Blo + (size_t)(n0+row)*EMBED + k0 + sl*8, Bl + cb*8);
      }
    }
    __syncthreads();

    bf16x8 ah[4], bh[4], al[4], bl[4];
#pragma unroll
    for (int i = 0; i < 4; ++i){
      int ra = wr*64 + i*16 + fr;
      int oa = ra*32 + (fk ^ swz4(ra))*8;
      ah[i] = *(const bf16x8*)&Ah[oa];
      if (full) al[i] = *(const bf16x8*)&Al[oa];
      int rb = wc*64 + i*16 + fr;
      int ob = rb*32 + (fk ^ swz4(rb))*8;
      bh[i] = *(const bf16x8*)&Bh[ob];
      if (full) bl[i] = *(const bf16x8*)&Bl[ob];
    }
#pragma unroll
    for (int i = 0; i < 4; ++i)
#pragma unroll
      for (int j = 0; j < 4; ++j){
        acc[i][j] = __builtin_amdgcn_mfma_f32_16x16x32_bf16(ah[i], bh[j], acc[i][j], 0,0,0);
        if (full){
          acc[i][j] = __builtin_amdgcn_mfma_f32_16x16x32_bf16(ah[i], bl[j], acc[i][j], 0,0,0);
          acc[i][j] = __builtin_amdgcn_mfma_f32_16x16x32_bf16(al[i], bh[j], acc[i][j], 0,0,0);
        }
      }
  }

  const int mat = (n0 + wc*64) >> 10;        // 0=Q 1=K 2=V (uniform per wave)
  const float QSCALE = 0.125f * 1.44269504089f;   // fold 1/sqrt(64) and log2(e)
#pragma unroll
  for (int i = 0; i < 4; ++i)
#pragma unroll
    for (int j = 0; j < 4; ++j)
#pragma unroll
      for (int r = 0; r < 4; ++r){
        int gm = m0 + wr*64 + i*16 + fk*4 + r;
        int gn = n0 + wc*64 + j*16 + fr;
        int col = gn & 1023;
        float v = acc[i][j][r];
        int b = gm >> 11, tt2 = gm & 2047, h = col >> 6, d = col & 63;
        if (mat == 2){
          vt[((size_t)(b*HEADS + h)*HDIM + d)*TT + tt2] = f2bf(v);
        } else {
          if (mat == 0) v *= QSCALE;
          size_t idx = ((size_t)(b*HEADS + h)*TT + tt2)*HDIM + d;
          u16 hi = f2bf(v);
          u16 lo = f2bf(v - bf2f(hi));
          if (mat == 0){ qhi[idx] = hi; qlo[idx] = lo; }
          else         { khi[idx] = hi; klo[idx] = lo; }
        }
      }
}

// ---------------- flash attention, MFMA, swapped QK^T ----------------
// S^T = K Q^T via mfma(Kfrag, Qfrag): rows=kv=(fk*4+r), cols=q=fr.
// Per-lane softmax state for q-row fr. Logits in log2 units (Q pre-scaled by log2e/8).
// Staging: global_load_lds direct; all loop-invariant addresses hoisted; setprio
// around MFMA clusters. launch_bounds(256,4): grid caps at 4 blocks/CU, allow 128 VGPR.
__global__ __launch_bounds__(256, 4)
void attn_mfma(const u16* __restrict__ Qhi, const u16* __restrict__ Qlo,
               const u16* __restrict__ Khi, const u16* __restrict__ Klo,
               const u16* __restrict__ Vt,  u16* __restrict__ ctx)
{
  __shared__ __align__(16) u16 smem[16384];   // 32 KB
  u16* Kh = smem;            // 4096 (aliases Q staging)
  u16* Kl = smem + 4096;     // 4096
  u16* Vs = smem + 8192;     // 4096
  u16* Ps = smem + 12288;    // 4096 (4 waves x 1024)
  const int t = threadIdx.x, lane = t & 63, w = t >> 6;
  const int fr = lane & 15, fk = lane >> 4;
  const int bh = blockIdx.y, q0 = blockIdx.x * 64;
  const size_t kbase = (size_t)bh * TT * HDIM;
  const size_t vbase = (size_t)bh * HDIM * TT;

  // stage Q (into K region), pull to registers
#pragma unroll
  for (int cc = 0; cc < 2; ++cc){
    int cb = w*128 + cc*64;
    int chunk = cb + lane;
    int row = chunk >> 3, slot = chunk & 7;
    int sl = slot ^ (row & 7);
    stage16(Qhi + kbase + (size_t)(q0+row)*HDIM + sl*8, Kh + cb*8);
    stage16(Qlo + kbase + (size_t)(q0+row)*HDIM + sl*8, Kl + cb*8);
  }
  __syncthreads();
  bf16x8 qh[2], ql[2];
#pragma unroll
  for (int ks = 0; ks < 2; ++ks){
    int row = w*16 + fr;
    int off = row*64 + ((ks*4 + fk) ^ (row & 7))*8;
    qh[ks] = *(const bf16x8*)&Kh[off];
    ql[ks] = *(const bf16x8*)&Kl[off];
  }

  // ---- hoisted loop invariants (constant-indexed arrays stay in registers) ----
  int offK[4][2], idxP[4], offP[2];
#pragma unroll
  for (int n = 0; n < 4; ++n){
#pragma unroll
    for (int ks = 0; ks < 2; ++ks){
      int row = n*16 + fr;
      offK[n][ks] = row*64 + ((ks*4 + fk) ^ (row & 7))*8;   // K and V read offsets
    }
    idxP[n] = w*1024 + fr*64 + ((n*2 + (fk >> 1)) ^ (fr & 7))*8 + (fk & 1)*4;
  }
#pragma unroll
  for (int ks = 0; ks < 2; ++ks)
    offP[ks] = w*1024 + fr*64 + ((ks*4 + fk) ^ (fr & 7))*8;

  int sdst[2];
  const u16 *sKh[2], *sKl[2], *sV[2];
#pragma unroll
  for (int cc = 0; cc < 2; ++cc){
    int chunk = w*128 + cc*64 + lane;
    int row = chunk >> 3, slot = chunk & 7;
    int sl = slot ^ (row & 7);
    sdst[cc] = chunk*8;
    sKh[cc] = Khi + kbase + (size_t)row*HDIM + sl*8;
    sKl[cc] = Klo + kbase + (size_t)row*HDIM + sl*8;
    sV [cc] = Vt  + vbase + (size_t)row*TT  + sl*8;
  }

  float mi = -1e30f, li = 0.f;
  f32x4 oacc[4];
#pragma unroll
  for (int n = 0; n < 4; ++n) oacc[n] = (f32x4){0.f,0.f,0.f,0.f};

  for (int kt = 0; kt < TT/64; ++kt){
    __syncthreads();   // K/V buffers free (first iter: q reg-loads drained)
#pragma unroll
    for (int cc = 0; cc < 2; ++cc){
      stage16(sKh[cc], Kh + sdst[cc]);  sKh[cc] += 64*HDIM;
      stage16(sKl[cc], Kl + sdst[cc]);  sKl[cc] += 64*HDIM;
      stage16(sV [cc], Vs + sdst[cc]);  sV [cc] += 64;
    }
    __syncthreads();

    // S^T = K Q^T (3-MFMA hi/lo), rows=kv, cols=q=fr
    f32x4 sacc[4];
#pragma unroll
    for (int n = 0; n < 4; ++n) sacc[n] = (f32x4){0.f,0.f,0.f,0.f};
    __builtin_amdgcn_s_setprio(1);
#pragma unroll
    for (int n = 0; n < 4; ++n)
#pragma unroll
      for (int ks = 0; ks < 2; ++ks){
        bf16x8 kh = *(const bf16x8*)&Kh[offK[n][ks]];
        bf16x8 kl = *(const bf16x8*)&Kl[offK[n][ks]];
        sacc[n] = __builtin_amdgcn_mfma_f32_16x16x32_bf16(kh, qh[ks], sacc[n], 0,0,0);
        sacc[n] = __builtin_amdgcn_mfma_f32_16x16x32_bf16(kl, qh[ks], sacc[n], 0,0,0);
        sacc[n] = __builtin_amdgcn_mfma_f32_16x16x32_bf16(kh, ql[ks], sacc[n], 0,0,0);
      }
    __builtin_amdgcn_s_setprio(0);

    // per-lane tile max over this lane's 16 values, then across the 4 fk-groups
    float mt = fmaxf(fmaxf(sacc[0][0], sacc[0][1]), fmaxf(sacc[0][2], sacc[0][3]));
#pragma unroll
    for (int n = 1; n < 4; ++n)
      mt = fmaxf(mt, fmaxf(fmaxf(sacc[n][0], sacc[n][1]), fmaxf(sacc[n][2], sacc[n][3])));
    mt = fmaxf(mt, __shfl_xor(mt, 16));
    mt = fmaxf(mt, __shfl_xor(mt, 32));

    // defer-max (log2 units; 11.54 ~ e^8)
    if (__any(mt > mi + 11.54f)){
      float mn = fmaxf(mi, mt);
      float sc = fexp2(mi - mn);
      mi = mn;
      li *= sc;
      float sct[4];
#pragma unroll
      for (int r = 0; r < 4; ++r) sct[r] = __shfl(sc, fk*4 + r);
#pragma unroll
      for (int n = 0; n < 4; ++n)
#pragma unroll
        for (int r = 0; r < 4; ++r) oacc[n][r] *= sct[r];
    }

    // P = 2^(S - mi) via raw v_exp_f32, in-lane sum + 2 shuffles
    float rs = 0.f;
#pragma unroll
    for (int n = 0; n < 4; ++n)
#pragma unroll
      for (int r = 0; r < 4; ++r){
        float p = fexp2(sacc[n][r] - mi);
        sacc[n][r] = p;
        rs += p;
      }
    rs += __shfl_xor(rs, 16);
    rs += __shfl_xor(rs, 32);
    li += rs;

    // pack P (bf16 pairs) and write 4x ds_write_b64 into row q=fr
#pragma unroll
    for (int n = 0; n < 4; ++n){
      u32 u0 = cvtpk(sacc[n][0], sacc[n][1]);
      u32 u1 = cvtpk(sacc[n][2], sacc[n][3]);
      uint2 pk; pk.x = u0; pk.y = u1;
      *(uint2*)&Ps[idxP[n]] = pk;
    }

    // O += P V  (pa rows=q=fr -> output rows (fk,r)=q; V rows=d -> output cols fr=d)
    __builtin_amdgcn_s_setprio(1);
#pragma unroll
    for (int ks = 0; ks < 2; ++ks){
      bf16x8 pa = *(const bf16x8*)&Ps[offP[ks]];
#pragma unroll
      for (int n = 0; n < 4; ++n){
        bf16x8 bv = *(const bf16x8*)&Vs[offK[n][ks]];
        oacc[n] = __builtin_amdgcn_mfma_f32_16x16x32_bf16(pa, bv, oacc[n], 0,0,0);
      }
    }
    __builtin_amdgcn_s_setprio(0);
  }

  // finalize: inv lives at q=fr lanes; transpose to (fk,r) rows
  float inv = 1.f / li;
  float invt[4];
#pragma unroll
  for (int r = 0; r < 4; ++r) invt[r] = __shfl(inv, fk*4 + r);

  int b = bh >> 4, h = bh & 15;
#pragma unroll
  for (int r = 0; r < 4; ++r){
    int q = q0 + w*16 + fk*4 + r;
#pragma unroll
    for (int n = 0; n < 4; ++n){
      int d = n*16 + fr;
      ctx[((size_t)(b*TT + q))*EMBED + h*HDIM + d] = f2bf(oacc[n][r]*invt[r]);
    }
  }
}

// ---------------- output projection: 64x128 tile, 512 blocks (2/CU) ----------------
// 4 waves, wave w owns cols [w*32, w*32+32): acc[4][2] (64 rows x 32 cols).
__global__ __launch_bounds__(256)
void outproj_gemm(const u16* __restrict__ Ab, const u16* __restrict__ Bb,
                  const float* __restrict__ bias, float* __restrict__ C)
{
  __shared__ __align__(16) u16 Ah[64*32], Bh[128*32];   // 12 KB
  const int t = threadIdx.x, lane = t & 63, w = t >> 6;
  const int fr = lane & 15, fk = lane >> 4;
  const int m0 = blockIdx.y * 64, n0 = blockIdx.x * 128;

  f32x4 acc[4][2];
#pragma unroll
  for (int i = 0; i < 4; ++i)
#pragma unroll
    for (int j = 0; j < 2; ++j) acc[i][j] = (f32x4){0.f,0.f,0.f,0.f};

  for (int k0 = 0; k0 < EMBED; k0 += 32){
    __syncthreads();
    { // A: 64x32, one 16B chunk per wave
      int s = w*64 + lane;                 // slot 0..255
      int row = s >> 2, slot = s & 3;
      int sl = slot ^ swz4(row);
      stage16(Ab + (size_t)(m0+row)*EMBED + k0 + sl*8, Ah + s*8);
    }
#pragma unroll
    for (int c = 0; c < 2; ++c){ // B: 128x32, two chunks per wave
      int s = (w*2 + c)*64 + lane;         // slot 0..511
      int row = s >> 2, slot = s & 3;
      int sl = slot ^ swz4(row);
      stage16(Bb + (size_t)(n0+row)*EMBED + k0 + sl*8, Bh + s*8);
    }
    __syncthreads();

    bf16x8 ah[4], bh[2];
#pragma unroll
    for (int i = 0; i < 4; ++i){
      int ra = i*16 + fr;
      ah[i] = *(const bf16x8*)&Ah[ra*32 + (fk ^ swz4(ra))*8];
    }
#pragma unroll
    for (int j = 0; j < 2; ++j){
      int rb = w*32 + j*16 + fr;
      bh[j] = *(const bf16x8*)&Bh[rb*32 + (fk ^ swz4(rb))*8];
    }
#pragma unroll
    for (int i = 0; i < 4; ++i)
#pragma unroll
      for (int j = 0; j < 2; ++j)
        acc[i][j] = __builtin_amdgcn_mfma_f32_16x16x32_bf16(ah[i], bh[j], acc[i][j], 0,0,0);
  }

#pragma unroll
  for (int i = 0; i < 4; ++i)
#pragma unroll
    for (int j = 0; j < 2; ++j)
#pragma unroll
      for (int r = 0; r < 4; ++r){
        int gm = m0 + i*16 + fk*4 + r;
        int gn = n0 + w*32 + j*16 + fr;
        C[(size_t)gm*EMBED + gn] = acc[i][j][r] + bias[gn];
      }
}

// ---------------- launch ----------------
extern "C" void kernel_launch(void* const* d_in, const int* in_sizes, int n_in,
                              void* d_out, int out_size, void* d_ws, size_t ws_size,
                              hipStream_t stream) {
  const float* x  = (const float*)d_in[0];
  const float* Wq = (const float*)d_in[1];
  const float* Aq = (const float*)d_in[2];
  const float* Bq = (const float*)d_in[3];
  const float* Wk = (const float*)d_in[4];
  const float* Ak = (const float*)d_in[5];
  const float* Bk = (const float*)d_in[6];
  const float* Wv = (const float*)d_in[7];
  const float* Av = (const float*)d_in[8];
  const float* Bv = (const float*)d_in[9];
  const float* Wo = (const float*)d_in[10];
  const float* bo = (const float*)d_in[11];
  float* out = (float*)d_out;

  char* ws = (char*)d_ws;
  const size_t MB = 1u << 20;
  u16* xhi  = (u16*)(ws + 0*MB);    // 8 MB (aliased by ctx later)
  u16* xlo  = (u16*)(ws + 8*MB);    // 8 MB
  u16* whi  = (u16*)(ws + 16*MB);   // 6 MB  [Wq;Wk;Wv] hi
  u16* wlo  = (u16*)(ws + 22*MB);   // 6 MB
  u16* wob  = (u16*)(ws + 28*MB);   // 2 MB
  u16* qhi  = (u16*)(ws + 30*MB);   // 8 MB
  u16* qlo  = (u16*)(ws + 38*MB);   // 8 MB
  u16* khi  = (u16*)(ws + 46*MB);   // 8 MB
  u16* klo  = (u16*)(ws + 54*MB);   // 8 MB
  u16* vt   = (u16*)(ws + 62*MB);   // 8 MB
  u16* ctx  = (u16*)(ws + 0*MB);    // 8 MB, over xhi (dead after qkv_gemm)

  dim3 blk(256);
  split_x_kernel<<<dim3(MTOT*EMBED/256), blk, 0, stream>>>(x, xhi, xlo);
  prep_weights_kernel<<<dim3(4096, 4), blk, 0, stream>>>(Wq, Wk, Wv, Wo, Aq, Ak, Av,
                                                         Bq, Bk, Bv, whi, wlo, wob);

  qkv_gemm<<<dim3(3*EMBED/128, MTOT/128), blk, 0, stream>>>(xhi, xlo, whi, wlo,
                                                            qhi, qlo, khi, klo, vt);

  attn_mfma<<<dim3(TT/64, BH), blk, 0, stream>>>(qhi, qlo, khi, klo, vt, ctx);

  outproj_gemm<<<dim3(EMBED/128, MTOT/64), blk, 0, stream>>>(ctx, wob, bo, out);
}